// Round 9
// baseline (220.868 us; speedup 1.0000x reference)
//
#include <hip/hip_runtime.h>
#include <math.h>

// Problem constants
#define HH 56
#define WW 56
#define NB 32
#define CC 256
#define PIX 3136               // 56*56
#define M_TOT 100352           // 32*3136
#define PADH 58
#define PADW 58
#define ACTQ_BYTES ((size_t)NB*PADH*PADW*CC)   // 27,553,792
#define WQ_BYTES ((size_t)9*CC*CC)             // 589,824
#define SBUF_BYTES ((size_t)M_TOT*CC*2)        // 51,380,224
#define BM 128
#define BN 128

typedef unsigned int u32;
typedef unsigned long long u64;
typedef int v4i __attribute__((ext_vector_type(4)));

// global_load_lds, width 16 (global -> LDS DMA; dest = wave base + lane*16)
typedef const __attribute__((address_space(1))) unsigned int* as1_u32p;
typedef __attribute__((address_space(3))) unsigned int* as3_u32p;
#define GLOAD_LDS16(g, l) \
  __builtin_amdgcn_global_load_lds((as1_u32p)(g), (as3_u32p)(l), 16, 0, 0)

// ---------------------------------------------------------------------------
// Pack weights: per-co mean (double), unbiased std, sw = 2^round(log2 mean|bw|),
// sign bytes wq[tap][co][ci] in {-1,+1}. Zeroes stat accumulators.
// ---------------------------------------------------------------------------
__global__ __launch_bounds__(256) void pack_weights_i8(
    const float* __restrict__ wt, signed char* __restrict__ wq,
    float* __restrict__ swv,
    long long* __restrict__ sumS, long long* __restrict__ sumSS) {
  int co = blockIdx.x;
  int t  = threadIdx.x;          // = ci
  int lane = t & 63, wid = t >> 6;

  float wv[9];
  const float* wp = wt + ((size_t)co*CC + t)*9;
  double psum = 0.0;
#pragma unroll
  for (int k = 0; k < 9; ++k) { wv[k] = wp[k]; psum += (double)wv[k]; }

  __shared__ double redm[4];
#pragma unroll
  for (int off = 32; off > 0; off >>= 1) psum += __shfl_xor(psum, off);
  if (lane == 0) redm[wid] = psum;
  __syncthreads();
  double mean = (redm[0]+redm[1]+redm[2]+redm[3]) * (1.0/2304.0);

  double pabs = 0.0, psq = 0.0;
#pragma unroll
  for (int k = 0; k < 9; ++k) {
    double d = (double)wv[k] - mean;
    pabs += fabs(d);
    psq  += d*d;
  }
#pragma unroll
  for (int off = 32; off > 0; off >>= 1) {
    pabs += __shfl_xor(pabs, off);
    psq  += __shfl_xor(psq,  off);
  }
  __shared__ double reda[4], redq[4];
  if (lane == 0) { reda[wid] = pabs; redq[wid] = psq; }
  __syncthreads();
  if (t == 0) {
    double sa = reda[0]+reda[1]+reda[2]+reda[3];
    double sq = redq[0]+redq[1]+redq[2]+redq[3];
    double stdv = sqrt(sq / 2303.0);                 // torch unbiased std
    double mabs = (sa * (1.0/2304.0)) / stdv;        // mean|bw|
    swv[co] = (float)exp2(rint(log2(mabs)));         // round half-to-even
    sumS[co]  = 0;
    sumSS[co] = 0;
  }
  // sign bytes: wq[k][co][ci]
#pragma unroll
  for (int k = 0; k < 9; ++k)
    wq[((size_t)k*CC + co)*CC + t] =
        (((double)wv[k] - mean) > 0.0) ? (signed char)1 : (signed char)-1;
}

// ---------------------------------------------------------------------------
// Pack activations: sign(x) -> i8 channel-last padded [n][ph][pw][ci].
// Border cells written as zeros here (memset fused away).
// ---------------------------------------------------------------------------
__global__ __launch_bounds__(256) void pack_acts_i8(
    const float* __restrict__ x, signed char* __restrict__ actq) {
  int n = blockIdx.y, tile = blockIdx.x;               // 53 tiles of 64 padded-pl
  int lane = threadIdx.x & 63, cw = threadIdx.x >> 6;  // cw: 64-ci group
  int pp = tile*64 + lane;
  if (pp >= PADH*PADW) return;
  int ph = pp / PADW, pw = pp - ph*PADW;
  signed char* dst = actq + ((size_t)(n*PADH + ph)*PADW + pw)*CC + cw*64;
  if (ph == 0 || ph == PADH-1 || pw == 0 || pw == PADW-1) {
    uint4 z = make_uint4(0u, 0u, 0u, 0u);
#pragma unroll
    for (int q = 0; q < 4; ++q) ((uint4*)dst)[q] = z;
    return;
  }
  int h = ph - 1, w = pw - 1;
  const float* xp = x + ((size_t)(n*CC + cw*64))*PIX + h*WW + w;
  u32 wrd[16];
#pragma unroll
  for (int c16 = 0; c16 < 16; ++c16) {
    u32 v = 0;
#pragma unroll
    for (int b = 0; b < 4; ++b) {
      float f = xp[(size_t)(c16*4 + b)*PIX];
      v |= (f > 0.0f ? 0x01u : 0xFFu) << (8*b);   // +1 / -1 as i8
    }
    wrd[c16] = v;
  }
#pragma unroll
  for (int q = 0; q < 4; ++q)
    ((uint4*)dst)[q] = make_uint4(wrd[4*q], wrd[4*q+1], wrd[4*q+2], wrd[4*q+3]);
}

// ---------------------------------------------------------------------------
// Binary implicit-GEMM conv, mfma_i32_16x16x64_i8. Block 128x128, grid
// (784, 2), 4 waves, wave tile 64x64 (16 MFMA/stage).
// Round 9: B DIRECT-TO-REGISTERS. LDS-port audit (R8's MfmaUtil calib ->
// i8 MFMA ~8cy -> MFMA pipe only ~25% busy): R3's binding pipe was the LDS
// port at ~84% (reads 96KB + DMA-writes 48KB per 2050cy across 2 blocks).
// wq is 576KB = permanently L2/L1-hot (unlike R4's 26MB actq), so B frags
// load straight from global into registers, DOUBLE-BUFFERED one full stage
// (~2000cy) ahead -> L1/L2 latency fully hidden. LDS now stages A only:
// 24KB/block-stage (was 72KB). Schedule = R6's proven single-barrier
// 3-buffer rotation (DMA(s+2) overwrites the stage-(s-1) buffer).
// vmcnt ledger (per-stage issue order [B(s+1) x4, A-DMA(s+2) x2]):
// at wait(s) outstanding = {A(s)?,B(s),A(s+1)} issued earlier + nothing
// younger than A(s) except B(s)4+A(s+1)2 -> steady vmcnt(6) drains A(s),
// keeps B(s+1) path clear; sched_barrier(0) after each barrier pins LOADB
// below the wait so the ledger stays exact. Tail: vmcnt(6),...,vmcnt(4).
// A keeps the XOR chunk-swizzle (0 bank conflicts, verified R1+).
// ---------------------------------------------------------------------------

// A-stage SN (tap SN>>2, k-chunk SN&3) into buffer (SN%3); 2 loads/thread.
#define STAGEA(SN) do {                                                   \
    int tn_ = (SN) >> 2, kn_ = (SN) & 3;                                  \
    int aoff_ = ((tn_/3 - 1)*PADW + (tn_%3 - 1))*CC + kn_*64;             \
    char* nb_ = (char*)lds + (((SN) % 3) << 13);                          \
    GLOAD_LDS16(pA0 + aoff_, nb_ + ldst);                                 \
    GLOAD_LDS16(pA1 + aoff_, nb_ + 4096 + ldst);                          \
  } while (0)

// B frags for stage SN direct from global into BF[0..3] (compiler-tracked
// loads; consumed next stage -> one full stage of latency hiding).
#define LOADB(SN, BF) do {                                                \
    int tn_ = (SN) >> 2, kn_ = (SN) & 3;                                  \
    int boff_ = tn_*65536 + kn_*64;                                       \
    BF[0] = *(const v4i*)(pBg + boff_);                                   \
    BF[1] = *(const v4i*)(pBg + boff_ + 4096);                            \
    BF[2] = *(const v4i*)(pBg + boff_ + 8192);                            \
    BF[3] = *(const v4i*)(pBg + boff_ + 12288);                           \
  } while (0)

// one K-stage: counted wait (A(s) landed) -> barrier -> pin -> B(s+1) reg
// loads + A-DMA(s+2) -> A frag ds_reads -> 16 MFMA on (af, BCUR).
#define STEP(S, BCUR, BNXT, WTXT, DOA, DOB) do {                          \
    asm volatile("s_waitcnt " WTXT ::: "memory");                         \
    __builtin_amdgcn_s_barrier();                                         \
    __builtin_amdgcn_sched_barrier(0);                                    \
    if (DOB) { LOADB((S) + 1, BNXT); }                                    \
    if (DOA) { STAGEA((S) + 2); }                                         \
    const char* cb_ = (const char*)lds + (((S) % 3) << 13);               \
    v4i af[4];                                                            \
    _Pragma("unroll")                                                     \
    for (int i_ = 0; i_ < 4; ++i_)                                        \
      af[i_] = *(const v4i*)(cb_ + (ar0 + i_*16 + lm)*64 + rdo);          \
    __builtin_amdgcn_s_setprio(1);                                        \
    _Pragma("unroll")                                                     \
    for (int j_ = 0; j_ < 4; ++j_)                                        \
      _Pragma("unroll")                                                   \
      for (int i_ = 0; i_ < 4; ++i_)                                      \
        acc[i_][j_] = __builtin_amdgcn_mfma_i32_16x16x64_i8(              \
            af[i_], BCUR[j_], acc[i_][j_], 0, 0, 0);                      \
    __builtin_amdgcn_s_setprio(0);                                        \
  } while (0)

template <bool S16>
__global__ __launch_bounds__(256, 2) void bconv_mfma(
    const signed char* __restrict__ actq, const signed char* __restrict__ wq,
    short* __restrict__ s16out, float* __restrict__ f32out,
    u64* __restrict__ sumS, u64* __restrict__ sumSS) {
  __shared__ char lds[24576] __attribute__((aligned(16)));  // 3 x A 8K
  __shared__ int colS[128], colQ[128];

  int t = threadIdx.x;
  int lane = t & 63, wv = t >> 6;
  int lm = lane & 15, quad = lane >> 4;
  int ar0 = (wv & 1) * 64;         // wave A-row base in tile
  int bc0 = (wv >> 1) * 64;        // wave B-col base in tile
  int Mbase = blockIdx.x * BM;
  int n0 = blockIdx.y * BN;

  if (t < 128) { colS[t] = 0; colQ[t] = 0; }

  // A staging: thread t -> rows r, r+64 (r = t>>2), 16B chunk c16 = t&3.
  // LDS dest LINEAR; global source chunk XOR-swizzled cs = c16 ^ ((r>>1)&3).
  int r = t >> 2, c16 = t & 3;
  int cs = c16 ^ ((r >> 1) & 3);
  const signed char *pA0, *pA1;
  {
    int P = Mbase + r;
    int n_ = P / PIX, pl_ = P % PIX, h_ = pl_ / WW, w_ = pl_ % WW;
    pA0 = actq + ((size_t)(n_*PADH + h_+1)*PADW + (w_+1))*CC + cs*16;
    P += 64;
    n_ = P / PIX; pl_ = P % PIX; h_ = pl_ / WW; w_ = pl_ % WW;
    pA1 = actq + ((size_t)(n_*PADH + h_+1)*PADW + (w_+1))*CC + cs*16;
  }
  int ldst = t*16;                 // LDS dest: [row][64B] contiguous in t

  // A read side: lane (lm,quad) wants global chunk=quad of row base+lm ->
  // LDS slot quad ^ ((row>>1)&3) == quad ^ ((lm>>1)&3) for 16-aligned bases
  int rdo = (quad ^ ((lm >> 1) & 3)) * 16;

  // B per-lane base: col = n0 + bc0 + lm, ci bytes quad*16.. of each 256B
  // row; per (stage,j) offset = tap*65536 + kq*64 + j*4096. Each frag load
  // = 16 cols x full 64B line window -> clean L1 lines, wq 576KB L2-hot.
  const signed char* pBg = wq + (size_t)(n0 + bc0 + lm)*CC + quad*16;

  v4i acc[4][4];
#pragma unroll
  for (int i = 0; i < 4; ++i)
#pragma unroll
    for (int j = 0; j < 4; ++j) acc[i][j] = 0;

  v4i b0[4], b1[4];                // B fragment double buffer (stage parity)

  // prologue: A(0),A(1) DMA (4 loads), then B(0) (4 reg loads)
  STAGEA(0);
  STAGEA(1);
  LOADB(0, b0);

  // 36 stages (tap = s>>2, kq = s&3). Buffer period 3 x parity 2 = 6.
#pragma unroll 1
  for (int s6 = 0; s6 < 30; s6 += 6) {
    STEP(s6+0, b0, b1, "vmcnt(6)", 1, 1);
    STEP(s6+1, b1, b0, "vmcnt(6)", 1, 1);
    STEP(s6+2, b0, b1, "vmcnt(6)", 1, 1);
    STEP(s6+3, b1, b0, "vmcnt(6)", 1, 1);
    STEP(s6+4, b0, b1, "vmcnt(6)", 1, 1);
    STEP(s6+5, b1, b0, "vmcnt(6)", 1, 1);
  }
  STEP(30, b0, b1, "vmcnt(6)", 1, 1);
  STEP(31, b1, b0, "vmcnt(6)", 1, 1);
  STEP(32, b0, b1, "vmcnt(6)", 1, 1);
  STEP(33, b1, b0, "vmcnt(6)", 1, 1);   // A(35), B(34)
  STEP(34, b0, b1, "vmcnt(6)", 0, 1);   // B(35); outstanding B(34)?,A(35)
  STEP(35, b1, b0, "vmcnt(4)", 0, 0);   // need A(35); younger = B(35) x4

  // ---- epilogue: store s16 (tile-local layout) / f32 + per-channel stats ----
  int Sl[4] = {0,0,0,0}, Ql[4] = {0,0,0,0};
  if (S16) {
    // sbuf layout: [tile = bx*2+cy][col 0..127][row 0..127] shorts.
    short* tb = s16out + ((size_t)(blockIdx.x*2 + blockIdx.y)) * (BM*BN);
#pragma unroll
    for (int i = 0; i < 4; ++i) {
      int rhat = ar0 + i*16 + quad*4;    // rows rhat..rhat+3 (4-aligned)
#pragma unroll
      for (int j = 0; j < 4; ++j) {
        int colo = bc0 + j*16 + lm;      // 0..127 (local)
        v4i a = acc[i][j];
        int2 pk;
        pk.x = (a.x & 0xFFFF) | (a.y << 16);
        pk.y = (a.z & 0xFFFF) | (a.w << 16);
        *(int2*)(tb + (size_t)colo*BM + rhat) = pk;
        Sl[j] += a.x + a.y + a.z + a.w;
        Ql[j] += a.x*a.x + a.y*a.y + a.z*a.z + a.w*a.w;
      }
    }
  } else {
#pragma unroll
    for (int i = 0; i < 4; ++i) {
      int R = Mbase + ar0 + i*16 + quad*4;   // rows R..R+3 (PIX%4==0)
      int nR = R / PIX, plR = R % PIX;
#pragma unroll
      for (int j = 0; j < 4; ++j) {
        int colo = n0 + bc0 + j*16 + lm;
        v4i a = acc[i][j];
        size_t idx = ((size_t)nR*CC + colo)*PIX + plR;
        *(float4*)(f32out + idx) =
            make_float4((float)a.x, (float)a.y, (float)a.z, (float)a.w);
        Sl[j] += a.x + a.y + a.z + a.w;
        Ql[j] += a.x*a.x + a.y*a.y + a.z*a.z + a.w*a.w;
      }
    }
  }
#pragma unroll
  for (int j = 0; j < 4; ++j) {
    int S = Sl[j], Q = Ql[j];
    S += __shfl_xor(S, 16); S += __shfl_xor(S, 32);   // reduce over quads
    Q += __shfl_xor(Q, 16); Q += __shfl_xor(Q, 32);
    if (quad == 0) {
      atomicAdd(&colS[bc0 + j*16 + lm], S);
      atomicAdd(&colQ[bc0 + j*16 + lm], Q);
    }
  }
  __syncthreads();
  if (t < 128) {
    atomicAdd(&sumS[n0 + t], (u64)(long long)colS[t]);   // 2's-comp wrap ok
    atomicAdd(&sumSS[n0 + t], (u64)(long long)colQ[t]);
  }
}

// ---------------------------------------------------------------------------
// Per-channel BN fold: out = clip(s*A + B)
// ---------------------------------------------------------------------------
__global__ void finalize_stats(
    const long long* __restrict__ sumS, const long long* __restrict__ sumSS,
    const float* __restrict__ swv,
    const float* __restrict__ gamma, const float* __restrict__ beta,
    float* __restrict__ AB) {
  int c = threadIdx.x;
  double mu  = (double)sumS[c]  / (double)M_TOT;
  double var = (double)sumSS[c] / (double)M_TOT - mu*mu;
  double sw  = (double)swv[c];
  double inv = 1.0 / sqrt(sw*sw*var + 1e-5);
  double scale = (double)gamma[c] * sw * inv;
  double shift = (double)beta[c] - scale * mu;
  AB[c]      = (float)scale;
  AB[CC + c] = (float)shift;
}

// Reads sbuf in tile-local layout [tile = bx*2+cy][col 128][row 128];
// writes NCHW f32. Linear 16B reads; 32B-contiguous out writes per thread.
__global__ __launch_bounds__(256) void bn_apply_s16(
    const short* __restrict__ s, float* __restrict__ out,
    const float* __restrict__ AB, int n8) {
  int i = blockIdx.x*256 + threadIdx.x;
  if (i >= n8) return;
  union { int4 v; short sh[8]; } u;
  u.v = ((const int4*)s)[i];
  int base   = i*8;
  int tile   = base >> 14;          // BM*BN = 16384 shorts per tile
  int within = base & 16383;
  int col7   = within >> 7;         // 0..127 (local col)
  int rh     = within & 127;        // row in tile, multiple of 8
  int bx = tile >> 1, cy = tile & 1;
  int col = cy*BN + col7;           // channel
  int R  = bx*BM + rh;              // global M index; 8-row group never
  int n_ = R / PIX, pl = R % PIX;   // straddles n (PIX%8==0)
  float a = AB[col], b = AB[CC + col];
  float* op = out + ((size_t)n_*CC + col)*PIX + pl;
  float4 o0, o1;
  o0.x = fminf(1.f, fmaxf(-1.f, (float)u.sh[0]*a + b));
  o0.y = fminf(1.f, fmaxf(-1.f, (float)u.sh[1]*a + b));
  o0.z = fminf(1.f, fmaxf(-1.f, (float)u.sh[2]*a + b));
  o0.w = fminf(1.f, fmaxf(-1.f, (float)u.sh[3]*a + b));
  o1.x = fminf(1.f, fmaxf(-1.f, (float)u.sh[4]*a + b));
  o1.y = fminf(1.f, fmaxf(-1.f, (float)u.sh[5]*a + b));
  o1.z = fminf(1.f, fmaxf(-1.f, (float)u.sh[6]*a + b));
  o1.w = fminf(1.f, fmaxf(-1.f, (float)u.sh[7]*a + b));
  ((float4*)op)[0] = o0;
  ((float4*)op)[1] = o1;
}

__global__ __launch_bounds__(256) void bn_apply_f32(
    float* __restrict__ out, const float* __restrict__ AB, int n4) {
  int i = blockIdx.x*256 + threadIdx.x;
  if (i >= n4) return;
  float4 v = ((float4*)out)[i];
  int c = ((i*4) / PIX) & (CC-1);
  float a = AB[c], b = AB[CC + c];
  v.x = fminf(1.f, fmaxf(-1.f, v.x*a + b));
  v.y = fminf(1.f, fmaxf(-1.f, v.y*a + b));
  v.z = fminf(1.f, fmaxf(-1.f, v.z*a + b));
  v.w = fminf(1.f, fmaxf(-1.f, v.w*a + b));
  ((float4*)out)[i] = v;
}

extern "C" void kernel_launch(void* const* d_in, const int* in_sizes, int n_in,
                              void* d_out, int out_size, void* d_ws, size_t ws_size,
                              hipStream_t stream) {
  (void)in_sizes; (void)n_in; (void)out_size;
  const float* x     = (const float*)d_in[0];
  const float* wt    = (const float*)d_in[1];
  const float* gamma = (const float*)d_in[2];
  const float* beta  = (const float*)d_in[3];
  float* out = (float*)d_out;

  char* ws = (char*)d_ws;
  size_t off = 0;
  signed char* actq = (signed char*)(ws + off);
  off += ACTQ_BYTES;             off = (off + 255) & ~(size_t)255;
  signed char* wq = (signed char*)(ws + off);
  off += WQ_BYTES;               off = (off + 255) & ~(size_t)255;
  float* swv = (float*)(ws + off); off += 1024;
  float* AB  = (float*)(ws + off); off += 2048;
  long long* sumS  = (long long*)(ws + off); off += 2048;
  long long* sumSS = (long long*)(ws + off); off += 2048;
  off = (off + 255) & ~(size_t)255;
  short* sbuf = (short*)(ws + off);
  bool s16 = (ws_size >= off + SBUF_BYTES);

  pack_weights_i8<<<256, 256, 0, stream>>>(wt, wq, swv, sumS, sumSS);
  pack_acts_i8<<<dim3(53, NB), 256, 0, stream>>>(x, actq);  // borders zeroed here
  if (s16) {
    bconv_mfma<true><<<dim3(M_TOT/BM, CC/BN), 256, 0, stream>>>(
        actq, wq, sbuf, nullptr, (u64*)sumS, (u64*)sumSS);
  } else {
    bconv_mfma<false><<<dim3(M_TOT/BM, CC/BN), 256, 0, stream>>>(
        actq, wq, nullptr, out, (u64*)sumS, (u64*)sumSS);
  }
  finalize_stats<<<1, 256, 0, stream>>>(sumS, sumSS, swv, gamma, beta, AB);
  if (s16) {
    bn_apply_s16<<<(M_TOT*CC/8 + 255)/256, 256, 0, stream>>>(
        sbuf, out, AB, M_TOT*CC/8);
  } else {
    bn_apply_f32<<<(M_TOT*CC/4 + 255)/256, 256, 0, stream>>>(
        out, AB, M_TOT*CC/4);
  }
}

// Round 10
// 151.945 us; speedup vs baseline: 1.4536x; 1.4536x over previous
//
#include <hip/hip_runtime.h>
#include <math.h>

// Problem constants
#define HH 56
#define WW 56
#define NB 32
#define CC 256
#define PIX 3136               // 56*56
#define M_TOT 100352           // 32*3136
#define PADH 58
#define PADW 58
#define ACTQ_BYTES ((size_t)NB*PADH*PADW*CC)   // 27,553,792
#define WQ_BYTES ((size_t)9*CC*CC)             // 589,824
#define SBUF_BYTES ((size_t)M_TOT*CC*2)        // 51,380,224
#define BM 128
#define BN 256

typedef unsigned int u32;
typedef unsigned long long u64;
typedef int v4i __attribute__((ext_vector_type(4)));

// global_load_lds, width 16 (global -> LDS DMA; dest = wave base + lane*16)
typedef const __attribute__((address_space(1))) unsigned int* as1_u32p;
typedef __attribute__((address_space(3))) unsigned int* as3_u32p;
#define GLOAD_LDS16(g, l) \
  __builtin_amdgcn_global_load_lds((as1_u32p)(g), (as3_u32p)(l), 16, 0, 0)

// ---------------------------------------------------------------------------
// Pack weights: per-co mean (double), unbiased std, sw = 2^round(log2 mean|bw|),
// sign bytes wq[tap][co][ci] in {-1,+1}. Zeroes stat accumulators.
// ---------------------------------------------------------------------------
__global__ __launch_bounds__(256) void pack_weights_i8(
    const float* __restrict__ wt, signed char* __restrict__ wq,
    float* __restrict__ swv,
    long long* __restrict__ sumS, long long* __restrict__ sumSS) {
  int co = blockIdx.x;
  int t  = threadIdx.x;          // = ci
  int lane = t & 63, wid = t >> 6;

  float wv[9];
  const float* wp = wt + ((size_t)co*CC + t)*9;
  double psum = 0.0;
#pragma unroll
  for (int k = 0; k < 9; ++k) { wv[k] = wp[k]; psum += (double)wv[k]; }

  __shared__ double redm[4];
#pragma unroll
  for (int off = 32; off > 0; off >>= 1) psum += __shfl_xor(psum, off);
  if (lane == 0) redm[wid] = psum;
  __syncthreads();
  double mean = (redm[0]+redm[1]+redm[2]+redm[3]) * (1.0/2304.0);

  double pabs = 0.0, psq = 0.0;
#pragma unroll
  for (int k = 0; k < 9; ++k) {
    double d = (double)wv[k] - mean;
    pabs += fabs(d);
    psq  += d*d;
  }
#pragma unroll
  for (int off = 32; off > 0; off >>= 1) {
    pabs += __shfl_xor(pabs, off);
    psq  += __shfl_xor(psq,  off);
  }
  __shared__ double reda[4], redq[4];
  if (lane == 0) { reda[wid] = pabs; redq[wid] = psq; }
  __syncthreads();
  if (t == 0) {
    double sa = reda[0]+reda[1]+reda[2]+reda[3];
    double sq = redq[0]+redq[1]+redq[2]+redq[3];
    double stdv = sqrt(sq / 2303.0);                 // torch unbiased std
    double mabs = (sa * (1.0/2304.0)) / stdv;        // mean|bw|
    swv[co] = (float)exp2(rint(log2(mabs)));         // round half-to-even
    sumS[co]  = 0;
    sumSS[co] = 0;
  }
  // sign bytes: wq[k][co][ci]
#pragma unroll
  for (int k = 0; k < 9; ++k)
    wq[((size_t)k*CC + co)*CC + t] =
        (((double)wv[k] - mean) > 0.0) ? (signed char)1 : (signed char)-1;
}

// ---------------------------------------------------------------------------
// Pack activations: sign(x) -> i8 channel-last padded [n][ph][pw][ci].
// Border cells written as zeros here (memset fused away).
// ---------------------------------------------------------------------------
__global__ __launch_bounds__(256) void pack_acts_i8(
    const float* __restrict__ x, signed char* __restrict__ actq) {
  int n = blockIdx.y, tile = blockIdx.x;               // 53 tiles of 64 padded-pl
  int lane = threadIdx.x & 63, cw = threadIdx.x >> 6;  // cw: 64-ci group
  int pp = tile*64 + lane;
  if (pp >= PADH*PADW) return;
  int ph = pp / PADW, pw = pp - ph*PADW;
  signed char* dst = actq + ((size_t)(n*PADH + ph)*PADW + pw)*CC + cw*64;
  if (ph == 0 || ph == PADH-1 || pw == 0 || pw == PADW-1) {
    uint4 z = make_uint4(0u, 0u, 0u, 0u);
#pragma unroll
    for (int q = 0; q < 4; ++q) ((uint4*)dst)[q] = z;
    return;
  }
  int h = ph - 1, w = pw - 1;
  const float* xp = x + ((size_t)(n*CC + cw*64))*PIX + h*WW + w;
  u32 wrd[16];
#pragma unroll
  for (int c16 = 0; c16 < 16; ++c16) {
    u32 v = 0;
#pragma unroll
    for (int b = 0; b < 4; ++b) {
      float f = xp[(size_t)(c16*4 + b)*PIX];
      v |= (f > 0.0f ? 0x01u : 0xFFu) << (8*b);   // +1 / -1 as i8
    }
    wrd[c16] = v;
  }
#pragma unroll
  for (int q = 0; q < 4; ++q)
    ((uint4*)dst)[q] = make_uint4(wrd[4*q], wrd[4*q+1], wrd[4*q+2], wrd[4*q+3]);
}

// ---------------------------------------------------------------------------
// Binary implicit-GEMM conv, mfma_i32_16x16x64_i8. Block 128x256 (grid 784),
// 4 waves, wave tile 64x128 (32 MFMA/stage). FINAL (= round-5 verified best,
// 151.7us total / ~93us conv):
// - 3-deep LDS pipeline, counted vmcnt(12) (never drained in main loop),
//   2 raw barriers/stage, XOR chunk-swizzle (0 bank conflicts), setprio
//   around the MFMA cluster, tile-local sbuf layout.
// Structural limit notes (rounds 0-9): LDS port ~84% busy (72KB/block-stage
// is tiling-minimal: every A/B byte DMA'd once/block, read by exactly 2
// waves); 7 schedule variants (drain, counted-vmcnt depth 2/3, reg-dbuf,
// single-barrier, 8-phase x2) all null or worse; removing LDS bytes via
// direct-global A (R4) or B (R9) trades for unhidden VMEM latency, -60%.
// ---------------------------------------------------------------------------

// stage SN (tap SN>>2, k-chunk SN&3) into buffer BUF (0/1/2)
// A: 8KB (128 rows x 64B), B: 16KB (256 cols x 64B); 6 gload_lds per thread.
#define STAGEM(SN, BUF) do {                                              \
    int tn_ = (SN) >> 2, kn_ = (SN) & 3;                                  \
    int aoff_ = ((tn_/3 - 1)*PADW + (tn_%3 - 1))*CC + kn_*64;             \
    int boff_ = tn_*65536 + kn_*64;                                       \
    char* nb_ = (char*)lds + (BUF)*24576;                                 \
    GLOAD_LDS16(pA0 + aoff_, nb_ + ldst);                                 \
    GLOAD_LDS16(pA1 + aoff_, nb_ + 4096 + ldst);                          \
    GLOAD_LDS16(pB0 + boff_, nb_ + 8192 + ldst);                          \
    GLOAD_LDS16(pB1 + boff_, nb_ + 12288 + ldst);                         \
    GLOAD_LDS16(pB2 + boff_, nb_ + 16384 + ldst);                         \
    GLOAD_LDS16(pB3 + boff_, nb_ + 20480 + ldst);                         \
  } while (0)

// one K-stage: wait stage S landed (counted), read frags, fence+barrier,
// prefetch stage S+3 into the freed buffer, 32 MFMAs under setprio(1).
#define STEPM(S, BUF, WTXT, DOSTAGE) do {                                 \
    asm volatile("s_waitcnt " WTXT ::: "memory");                         \
    __builtin_amdgcn_s_barrier();                                         \
    const char* cb_ = (const char*)lds + (BUF)*24576;                     \
    v4i af[4], bf[8];                                                     \
    _Pragma("unroll")                                                     \
    for (int i = 0; i < 4; ++i)                                           \
      af[i] = *(const v4i*)(cb_ + (ar0 + i*16 + lm)*64 + rdo);            \
    _Pragma("unroll")                                                     \
    for (int j = 0; j < 8; ++j)                                           \
      bf[j] = *(const v4i*)(cb_ + 8192 + (bc0 + j*16 + lm)*64 + rdo);     \
    asm volatile("s_waitcnt lgkmcnt(0)" ::: "memory");                    \
    __builtin_amdgcn_s_barrier();                                         \
    if (DOSTAGE) { STAGEM((S) + 3, BUF); }                                \
    __builtin_amdgcn_s_setprio(1);                                        \
    _Pragma("unroll")                                                     \
    for (int i = 0; i < 4; ++i)                                           \
      _Pragma("unroll")                                                   \
      for (int j = 0; j < 8; ++j)                                         \
        acc[i][j] = __builtin_amdgcn_mfma_i32_16x16x64_i8(af[i], bf[j],   \
                                                          acc[i][j], 0, 0, 0); \
    __builtin_amdgcn_s_setprio(0);                                        \
  } while (0)

template <bool S16>
__global__ __launch_bounds__(256, 2) void bconv_mfma(
    const signed char* __restrict__ actq, const signed char* __restrict__ wq,
    short* __restrict__ s16out, float* __restrict__ f32out,
    u64* __restrict__ sumS, u64* __restrict__ sumSS) {
  __shared__ char lds[73728] __attribute__((aligned(16)));  // 3 x (A 8K | B 16K)
  __shared__ int colS[256], colQ[256];

  int t = threadIdx.x;
  int lane = t & 63, wv = t >> 6;
  int lm = lane & 15, quad = lane >> 4;
  int ar0 = (wv & 1) * 64;         // wave A-row base in tile (2 row groups)
  int bc0 = (wv >> 1) * 128;       // wave B-col base in tile (2 col groups)
  int Mbase = blockIdx.x * BM;

  colS[t] = 0; colQ[t] = 0;

  // staging: thread t -> A rows r, r+64 / B cols r, r+64, r+128, r+192.
  // LDS dest is LINEAR slot (row, c16); global source chunk is XOR-swizzled
  // cs = c16 ^ ((r>>1)&3)  (row+64k keeps the same key).
  int r = t >> 2, c16 = t & 3;
  int cs = c16 ^ ((r >> 1) & 3);
  const signed char *pA0, *pA1;
  {
    int P = Mbase + r;
    int n_ = P / PIX, pl_ = P % PIX, h_ = pl_ / WW, w_ = pl_ % WW;
    pA0 = actq + ((size_t)(n_*PADH + h_+1)*PADW + (w_+1))*CC + cs*16;
    P += 64;
    n_ = P / PIX; pl_ = P % PIX; h_ = pl_ / WW; w_ = pl_ % WW;
    pA1 = actq + ((size_t)(n_*PADH + h_+1)*PADW + (w_+1))*CC + cs*16;
  }
  const signed char* pB0 = wq + (size_t)r*CC + cs*16;
  const signed char* pB1 = pB0 +  64*CC;
  const signed char* pB2 = pB0 + 128*CC;
  const signed char* pB3 = pB0 + 192*CC;
  int ldst = t*16;                 // LDS dest: [row][64B] contiguous in t

  // read side: lane (lm,quad) wants global chunk=quad of row ..+lm ->
  // LDS slot quad ^ ((row>>1)&3); (row>>1)&3 == (lm>>1)&3 for 16-aligned bases
  int rdo = (quad ^ ((lm >> 1) & 3)) * 16;

  v4i acc[4][8];
#pragma unroll
  for (int i = 0; i < 4; ++i)
#pragma unroll
    for (int j = 0; j < 8; ++j) acc[i][j] = 0;

  // prologue: fill the 3-deep pipeline (18 loads in flight)
  STAGEM(0, 0);
  STAGEM(1, 1);
  STAGEM(2, 2);

  // stage s: tap = s>>2 (0..8), kq = s&3 (64B k-chunk within tap); 36 stages.
  // steady state: wait vmcnt(12) -> stage s landed, 2 stages (12 loads)
  // stay in flight across the barriers.
#pragma unroll 1
  for (int s = 0; s < 33; s += 3) {
    STEPM(s,     0, "vmcnt(12)", true);
    STEPM(s + 1, 1, "vmcnt(12)", true);
    STEPM(s + 2, 2, "vmcnt(12)", true);
  }
  STEPM(33, 0, "vmcnt(12)", false);  // S34,S35 in flight (12) -> drains S33
  STEPM(34, 1, "vmcnt(6)",  false);  // S35 in flight (6) -> drains S34
  STEPM(35, 2, "vmcnt(0)",  false);  // drain

  // ---- epilogue: store s16 (tile-local layout) / f32 + per-channel stats ----
  int Sl[8] = {0,0,0,0,0,0,0,0}, Ql[8] = {0,0,0,0,0,0,0,0};
  if (S16) {
    // sbuf layout: [tile][col 0..255][row 0..127] shorts; dense tile writes.
    short* tb = s16out + (size_t)blockIdx.x * (BM*BN);
#pragma unroll
    for (int i = 0; i < 4; ++i) {
      int rhat = ar0 + i*16 + quad*4;    // rows rhat..rhat+3 (4-aligned)
#pragma unroll
      for (int j = 0; j < 8; ++j) {
        int colo = bc0 + j*16 + lm;
        v4i a = acc[i][j];
        int2 pk;
        pk.x = (a.x & 0xFFFF) | (a.y << 16);
        pk.y = (a.z & 0xFFFF) | (a.w << 16);
        *(int2*)(tb + (size_t)colo*BM + rhat) = pk;
        Sl[j] += a.x + a.y + a.z + a.w;
        Ql[j] += a.x*a.x + a.y*a.y + a.z*a.z + a.w*a.w;
      }
    }
  } else {
#pragma unroll
    for (int i = 0; i < 4; ++i) {
      int R = Mbase + ar0 + i*16 + quad*4;   // rows R..R+3 (PIX%4==0)
      int nR = R / PIX, plR = R % PIX;
#pragma unroll
      for (int j = 0; j < 8; ++j) {
        int colo = bc0 + j*16 + lm;
        v4i a = acc[i][j];
        size_t idx = ((size_t)nR*CC + colo)*PIX + plR;
        *(float4*)(f32out + idx) =
            make_float4((float)a.x, (float)a.y, (float)a.z, (float)a.w);
        Sl[j] += a.x + a.y + a.z + a.w;
        Ql[j] += a.x*a.x + a.y*a.y + a.z*a.z + a.w*a.w;
      }
    }
  }
#pragma unroll
  for (int j = 0; j < 8; ++j) {
    int S = Sl[j], Q = Ql[j];
    S += __shfl_xor(S, 16); S += __shfl_xor(S, 32);   // reduce over quads
    Q += __shfl_xor(Q, 16); Q += __shfl_xor(Q, 32);
    if (quad == 0) {
      atomicAdd(&colS[bc0 + j*16 + lm], S);
      atomicAdd(&colQ[bc0 + j*16 + lm], Q);
    }
  }
  __syncthreads();
  atomicAdd(&sumS[t], (u64)(long long)colS[t]);   // 2's-comp wrap ok
  atomicAdd(&sumSS[t], (u64)(long long)colQ[t]);
}

// ---------------------------------------------------------------------------
// Per-channel BN fold: out = clip(s*A + B)
// ---------------------------------------------------------------------------
__global__ void finalize_stats(
    const long long* __restrict__ sumS, const long long* __restrict__ sumSS,
    const float* __restrict__ swv,
    const float* __restrict__ gamma, const float* __restrict__ beta,
    float* __restrict__ AB) {
  int c = threadIdx.x;
  double mu  = (double)sumS[c]  / (double)M_TOT;
  double var = (double)sumSS[c] / (double)M_TOT - mu*mu;
  double sw  = (double)swv[c];
  double inv = 1.0 / sqrt(sw*sw*var + 1e-5);
  double scale = (double)gamma[c] * sw * inv;
  double shift = (double)beta[c] - scale * mu;
  AB[c]      = (float)scale;
  AB[CC + c] = (float)shift;
}

// Reads sbuf in tile-local layout [tile][col 256][row 128]; writes NCHW f32.
// Thread i handles 8 consecutive rows of one (tile,col): linear 16B read;
// out writes 32B contiguous per thread, 512B runs per 16 consecutive threads.
__global__ __launch_bounds__(256) void bn_apply_s16(
    const short* __restrict__ s, float* __restrict__ out,
    const float* __restrict__ AB, int n8) {
  int i = blockIdx.x*256 + threadIdx.x;
  if (i >= n8) return;
  union { int4 v; short sh[8]; } u;
  u.v = ((const int4*)s)[i];
  int base   = i*8;
  int tile   = base >> 15;          // BM*BN = 32768 shorts per tile
  int within = base & 32767;
  int col    = within >> 7;         // 0..255  (channel)
  int rh     = within & 127;        // row in tile, multiple of 8
  int R  = tile*BM + rh;            // global M index; 8-row group never
  int n_ = R / PIX, pl = R % PIX;   // straddles n (PIX%8==0, BM%8==0)
  float a = AB[col], b = AB[CC + col];
  float* op = out + ((size_t)n_*CC + col)*PIX + pl;
  float4 o0, o1;
  o0.x = fminf(1.f, fmaxf(-1.f, (float)u.sh[0]*a + b));
  o0.y = fminf(1.f, fmaxf(-1.f, (float)u.sh[1]*a + b));
  o0.z = fminf(1.f, fmaxf(-1.f, (float)u.sh[2]*a + b));
  o0.w = fminf(1.f, fmaxf(-1.f, (float)u.sh[3]*a + b));
  o1.x = fminf(1.f, fmaxf(-1.f, (float)u.sh[4]*a + b));
  o1.y = fminf(1.f, fmaxf(-1.f, (float)u.sh[5]*a + b));
  o1.z = fminf(1.f, fmaxf(-1.f, (float)u.sh[6]*a + b));
  o1.w = fminf(1.f, fmaxf(-1.f, (float)u.sh[7]*a + b));
  ((float4*)op)[0] = o0;
  ((float4*)op)[1] = o1;
}

__global__ __launch_bounds__(256) void bn_apply_f32(
    float* __restrict__ out, const float* __restrict__ AB, int n4) {
  int i = blockIdx.x*256 + threadIdx.x;
  if (i >= n4) return;
  float4 v = ((float4*)out)[i];
  int c = ((i*4) / PIX) & (CC-1);
  float a = AB[c], b = AB[CC + c];
  v.x = fminf(1.f, fmaxf(-1.f, v.x*a + b));
  v.y = fminf(1.f, fmaxf(-1.f, v.y*a + b));
  v.z = fminf(1.f, fmaxf(-1.f, v.z*a + b));
  v.w = fminf(1.f, fmaxf(-1.f, v.w*a + b));
  ((float4*)out)[i] = v;
}

extern "C" void kernel_launch(void* const* d_in, const int* in_sizes, int n_in,
                              void* d_out, int out_size, void* d_ws, size_t ws_size,
                              hipStream_t stream) {
  (void)in_sizes; (void)n_in; (void)out_size;
  const float* x     = (const float*)d_in[0];
  const float* wt    = (const float*)d_in[1];
  const float* gamma = (const float*)d_in[2];
  const float* beta  = (const float*)d_in[3];
  float* out = (float*)d_out;

  char* ws = (char*)d_ws;
  size_t off = 0;
  signed char* actq = (signed char*)(ws + off);
  off += ACTQ_BYTES;             off = (off + 255) & ~(size_t)255;
  signed char* wq = (signed char*)(ws + off);
  off += WQ_BYTES;               off = (off + 255) & ~(size_t)255;
  float* swv = (float*)(ws + off); off += 1024;
  float* AB  = (float*)(ws + off); off += 2048;
  long long* sumS  = (long long*)(ws + off); off += 2048;
  long long* sumSS = (long long*)(ws + off); off += 2048;
  off = (off + 255) & ~(size_t)255;
  short* sbuf = (short*)(ws + off);
  bool s16 = (ws_size >= off + SBUF_BYTES);

  pack_weights_i8<<<256, 256, 0, stream>>>(wt, wq, swv, sumS, sumSS);
  pack_acts_i8<<<dim3(53, NB), 256, 0, stream>>>(x, actq);  // borders zeroed here
  if (s16) {
    bconv_mfma<true><<<dim3(M_TOT/BM, 1), 256, 0, stream>>>(
        actq, wq, sbuf, nullptr, (u64*)sumS, (u64*)sumSS);
  } else {
    bconv_mfma<false><<<dim3(M_TOT/BM, 1), 256, 0, stream>>>(
        actq, wq, nullptr, out, (u64*)sumS, (u64*)sumSS);
  }
  finalize_stats<<<1, 256, 0, stream>>>(sumS, sumSS, swv, gamma, beta, AB);
  if (s16) {
    bn_apply_s16<<<(M_TOT*CC/8 + 255)/256, 256, 0, stream>>>(
        sbuf, out, AB, M_TOT*CC/8);
  } else {
    bn_apply_f32<<<(M_TOT*CC/4 + 255)/256, 256, 0, stream>>>(
        out, AB, M_TOT*CC/4);
  }
}